// Round 8
// baseline (128.145 us; speedup 1.0000x reference)
//
#include <hip/hip_runtime.h>

#define T_SEQ 4096
#define BATCH 4
#define DD 128
#define BT (BATCH * T_SEQ)

typedef __bf16 bf16x8 __attribute__((ext_vector_type(8)));
typedef float f32x4 __attribute__((ext_vector_type(4)));

__device__ inline bf16x8 ld8(const unsigned short* p) {
  return *reinterpret_cast<const bf16x8*>(p);
}
__device__ inline unsigned short bfc(float f) {
  __bf16 v = (__bf16)f;
  return __builtin_bit_cast(unsigned short, v);
}

#define MFMA(a, b, c) __builtin_amdgcn_mfma_f32_16x16x32_bf16((a), (b), (c), 0, 0, 0)

// ---- W (128x128 f32, [d][u]) -> frag-major bf16:
// F[((n0*4+c)*64 + lane)*8 + j] = W[(c*32+g*8+j)*128 + n0*16+t], lane=(g<<4)|t.
__global__ void wt_kernel(const float* __restrict__ Wq, const float* __restrict__ Wk,
                          const float* __restrict__ Wv,
                          unsigned short* __restrict__ fq, unsigned short* __restrict__ fk,
                          unsigned short* __restrict__ fv) {
  const float* W = (blockIdx.y == 0) ? Wq : (blockIdx.y == 1) ? Wk : Wv;
  unsigned short* F = (blockIdx.y == 0) ? fq : (blockIdx.y == 1) ? fk : fv;
  int e = blockIdx.x * 256 + threadIdx.x;          // 0..16383
  int j = e & 7, lane = (e >> 3) & 63, nc = e >> 9;
  int c = nc & 3, n0 = nc >> 2;
  int t = lane & 15, g = lane >> 4;
  F[e] = bfc(W[(c * 32 + g * 8 + j) * 128 + n0 * 16 + t]);
}

// ---- projections, W-STATIONARY ----
// qf[((tile16*4+c)*64 + (G<<4|m))*8 + e] = Q[tile16*16+m][c*32+G*8+e] * (1/64)
// kf[(((j32*2+i)*4+c)*64 + (G<<4|tp))*8 + e] = K[j32*32+4i+kappa(tp)][c*32+G*8+e]
// vt2: V[key][u] at chunk*4096 + (u>>4)*512 + ((kk>>3)*16 + (u&15))*8 + (kk&7),
//      chunk=key>>5, kk=key&31  => attn's B-frag load is flat lane*8 (coalesced).
__global__ __launch_bounds__(256) void proj_kernel(
    const float* __restrict__ X,
    const unsigned short* __restrict__ fq,
    const unsigned short* __restrict__ fk,
    const unsigned short* __restrict__ fv,
    unsigned short* __restrict__ qf,
    unsigned short* __restrict__ kf,
    unsigned short* __restrict__ vt) {
  const int tid = threadIdx.x;
  const int w = tid >> 6, lane = tid & 63;
  const int t = lane & 15, g = lane >> 4;
  const int r0 = blockIdx.x * 32;   // 512 blocks x 32 rows

  __shared__ unsigned short xs[2][16 * 136];

  // resident W fragments: strips n0/u0 in {w, w+4}
  bf16x8 wq[2][4], wk[2][4], wv[2][4];
#pragma unroll
  for (int s = 0; s < 2; ++s)
#pragma unroll
    for (int c = 0; c < 4; ++c) {
      int fo = (((w + s * 4) * 4 + c) * 64 + lane) * 8;
      wq[s][c] = ld8(fq + fo);
      wk[s][c] = ld8(fk + fo);
      wv[s][c] = ld8(fv + fo);
    }

  // stage both 16-row X subtiles, coalesced
#pragma unroll
  for (int sub = 0; sub < 2; ++sub) {
    int r = tid >> 4, cb = tid & 15;
    const float* xp = X + (size_t)(r0 + sub * 16 + r) * DD + cb * 8;
    float4 lo = *reinterpret_cast<const float4*>(xp);
    float4 hi = *reinterpret_cast<const float4*>(xp + 4);
    bf16x8 tmp;
    tmp[0] = (__bf16)lo.x; tmp[1] = (__bf16)lo.y; tmp[2] = (__bf16)lo.z; tmp[3] = (__bf16)lo.w;
    tmp[4] = (__bf16)hi.x; tmp[5] = (__bf16)hi.y; tmp[6] = (__bf16)hi.z; tmp[7] = (__bf16)hi.w;
    *reinterpret_cast<bf16x8*>(&xs[sub][r * 136 + cb * 8]) = tmp;
  }
  __syncthreads();

#pragma unroll
  for (int sub = 0; sub < 2; ++sub) {
    const int r0s = r0 + sub * 16;
    bf16x8 x[4];
#pragma unroll
    for (int c = 0; c < 4; ++c)
      x[c] = ld8(&xs[sub][t * 136 + c * 32 + g * 8]);

    // Q, K strips
#pragma unroll
    for (int s = 0; s < 2; ++s) {
      const int n0 = w + s * 4;
      f32x4 aq = {0.f, 0.f, 0.f, 0.f}, ak = {0.f, 0.f, 0.f, 0.f};
#pragma unroll
      for (int c = 0; c < 4; ++c) {
        aq = MFMA(x[c], wq[s][c], aq);
        ak = MFMA(x[c], wk[s][c], ak);
      }
      const int cP = n0 >> 1;
      const int Gp = ((n0 & 1) << 1) | (t >> 3);
      const int ep = t & 7;
#pragma unroll
      for (int r = 0; r < 4; ++r) {
        int row = r0s + g * 4 + r;
        size_t qoff = ((size_t)((row >> 4) * 4 + cP) * 64 + ((Gp << 4) | (row & 15))) * 8 + ep;
        qf[qoff] = bfc(aq[r] * 0.015625f);   // fold 1/sqrt(4096)
        int tp = (row & 3) | (((row >> 3) & 3) << 2);
        size_t koff =
            ((size_t)(((row >> 5) * 2 + ((row >> 2) & 1)) * 4 + cP) * 64 + ((Gp << 4) | tp)) * 8 +
            ep;
        kf[koff] = bfc(ak[r]);
      }
    }

    // V strips -> vt2 layout
    const int key = r0s + t;
    const int kk = key & 31;
    const size_t vbase = (size_t)(key >> 5) * 4096 + (size_t)(kk >> 3) * 128 + (kk & 7);
#pragma unroll
    for (int s = 0; s < 2; ++s) {
      const int u0 = w + s * 4;
      f32x4 av = {0.f, 0.f, 0.f, 0.f};
#pragma unroll
      for (int c = 0; c < 4; ++c)
        av = MFMA(wv[s][c], x[c], av);
#pragma unroll
      for (int r = 0; r < 4; ++r)
        vt[vbase + (size_t)u0 * 512 + (g * 4 + r) * 8] = bfc(av[r]);
    }
  }
}

// ---- flash attention: 64 queries/wave (4 q-tiles share every K/V load).
// 256 blocks (1/CU), batch pinned to an XCD pair, 4 waves slice chunks mod 4.
// All inner-loop loads are contiguous coalesced 1-KB streams (vt2 layout).
// K+V register prefetch; partials add (no online max; |s| <= ~2);
// staged 4-way LDS combine at the end.
__global__ __launch_bounds__(256, 1) void attn_kernel(
    const unsigned short* __restrict__ qf,
    const unsigned short* __restrict__ kf,
    const unsigned short* __restrict__ vt,
    float* __restrict__ out) {
  const int tid = threadIdx.x;
  const int w = tid >> 6, lane = tid & 63;
  const int t = lane & 15, G = lane >> 4;
  const int bi = blockIdx.x;
  const int xcd = bi & 7;                      // assumed round-robin XCD mapping
  const int b = xcd >> 1;                      // batch pinned to an XCD pair
  const int wi = ((bi >> 3) << 1) | (xcd & 1); // 0..63 within batch
  const int gamma = 63 - wi;                   // biggest groups dispatch first
  const int q0 = gamma * 64;
  const int nch = 2 * gamma + 2;               // 32-key chunks touching causal region

  const unsigned short* kfb = kf + (size_t)b * 128 * 4096;
  const unsigned short* vtb = vt + (size_t)b * 128 * 4096;

  // Q fragments for tiles 4g..4g+3: 16 coalesced 1-KB loads
  bf16x8 qa[4][4];
#pragma unroll
  for (int p = 0; p < 4; ++p)
#pragma unroll
    for (int c = 0; c < 4; ++c)
      qa[p][c] = ld8(qf + ((size_t)((b * 256 + 4 * gamma + p) * 4 + c) * 64 + lane) * 8);

  f32x4 O[4][8];
#pragma unroll
  for (int p = 0; p < 4; ++p)
#pragma unroll
    for (int u0 = 0; u0 < 8; ++u0) O[p][u0] = (f32x4){0.f, 0.f, 0.f, 0.f};
  float ls[4] = {0.f, 0.f, 0.f, 0.f};

  int j = w;
  bf16x8 kc[8], vc[8];
  if (j < nch) {
    const unsigned short* kblk = kfb + (size_t)j * 4096;
    const unsigned short* vblk = vtb + (size_t)j * 4096;
#pragma unroll
    for (int ci = 0; ci < 8; ++ci) {
      kc[ci] = ld8(kblk + ci * 512 + lane * 8);
      vc[ci] = ld8(vblk + ci * 512 + lane * 8);
    }
  }

  for (; j < nch; j += 4) {
    const bool hn = (j + 4) < nch;
    bf16x8 kn[8], vn[8];
    if (hn) {  // prefetch next chunk (K and V) across the compute
      const unsigned short* kb2 = kfb + (size_t)(j + 4) * 4096;
      const unsigned short* vb2 = vtb + (size_t)(j + 4) * 4096;
#pragma unroll
      for (int ci = 0; ci < 8; ++ci) {
        kn[ci] = ld8(kb2 + ci * 512 + lane * 8);
        vn[ci] = ld8(vb2 + ci * 512 + lane * 8);
      }
    }

    // S^T = K Q^T for 32 keys x 64 queries
    f32x4 s0[4], s1[4];
#pragma unroll
    for (int p = 0; p < 4; ++p) {
      s0[p] = (f32x4){0.f, 0.f, 0.f, 0.f};
      s1[p] = (f32x4){0.f, 0.f, 0.f, 0.f};
    }
#pragma unroll
    for (int c = 0; c < 4; ++c)
#pragma unroll
      for (int p = 0; p < 4; ++p) {
        s0[p] = MFMA(kc[c], qa[p][c], s0[p]);
        s1[p] = MFMA(kc[4 + c], qa[p][c], s1[p]);
      }

    const int j0 = j * 32;
    bf16x8 pb[4];
    if (j < 2 * gamma) {  // interior chunk: no mask anywhere
#pragma unroll
      for (int p = 0; p < 4; ++p)
#pragma unroll
        for (int r = 0; r < 4; ++r) {
          float e0 = __expf(s0[p][r]);
          float e1 = __expf(s1[p][r]);
          ls[p] += e0 + e1;
          pb[p][r] = (__bf16)e0;
          pb[p][r + 4] = (__bf16)e1;
        }
    } else {  // diagonal chunks: causal mask
#pragma unroll
      for (int p = 0; p < 4; ++p) {
        const int lim = q0 + p * 16 + t;
#pragma unroll
        for (int r = 0; r < 4; ++r) {
          int k0 = j0 + G * 8 + r;
          float e0 = (k0 <= lim) ? __expf(s0[p][r]) : 0.f;
          float e1 = (k0 + 4 <= lim) ? __expf(s1[p][r]) : 0.f;
          ls[p] += e0 + e1;
          pb[p][r] = (__bf16)e0;
          pb[p][r + 4] = (__bf16)e1;
        }
      }
    }

    // O += P V  (vc[u0] = B[k=G*8+j][n=t] = V[key][u0*16+t] under vt2)
#pragma unroll
    for (int u0 = 0; u0 < 8; ++u0)
#pragma unroll
      for (int p = 0; p < 4; ++p)
        O[p][u0] = MFMA(pb[p], vc[u0], O[p][u0]);

    if (hn) {
#pragma unroll
      for (int ci = 0; ci < 8; ++ci) { kc[ci] = kn[ci]; vc[ci] = vn[ci]; }
    }
  }

  // staged 4-way combine: one q-tile p at a time (28 KB LDS, partials add)
  __shared__ float cmb[3][64][36];
#pragma unroll 1
  for (int p = 0; p < 4; ++p) {
    __syncthreads();
    if (w > 0) {
#pragma unroll
      for (int u0 = 0; u0 < 8; ++u0)
        *reinterpret_cast<f32x4*>(&cmb[w - 1][lane][u0 * 4]) = O[p][u0];
      cmb[w - 1][lane][32] = ls[p];
    }
    __syncthreads();
    if (w == 0) {
      f32x4 acc[8];
#pragma unroll
      for (int u0 = 0; u0 < 8; ++u0) acc[u0] = O[p][u0];
      float lt = ls[p];
#pragma unroll
      for (int ww = 0; ww < 3; ++ww) {
#pragma unroll
        for (int u0 = 0; u0 < 8; ++u0) {
          f32x4 q4 = *reinterpret_cast<const f32x4*>(&cmb[ww][lane][u0 * 4]);
          acc[u0][0] += q4[0]; acc[u0][1] += q4[1];
          acc[u0][2] += q4[2]; acc[u0][3] += q4[3];
        }
        lt += cmb[ww][lane][32];
      }
      // row sums: lanes {t,t+16,t+32,t+48} hold partials for query t of tile p
      lt += __shfl_xor(lt, 16);
      lt += __shfl_xor(lt, 32);
      float linv[4];
#pragma unroll
      for (int r = 0; r < 4; ++r) linv[r] = 1.0f / __shfl(lt, G * 4 + r);
      float* op = out + ((size_t)(b * T_SEQ + q0 + p * 16 + G * 4)) * DD + t;
#pragma unroll
      for (int u0 = 0; u0 < 8; ++u0)
#pragma unroll
        for (int r = 0; r < 4; ++r)
          op[(size_t)r * DD + u0 * 16] = acc[u0][r] * linv[r];
    }
  }
}

extern "C" void kernel_launch(void* const* d_in, const int* in_sizes, int n_in,
                              void* d_out, int out_size, void* d_ws, size_t ws_size,
                              hipStream_t stream) {
  const float* X  = (const float*)d_in[0];
  const float* Wq = (const float*)d_in[1];
  const float* Wk = (const float*)d_in[2];
  const float* Wv = (const float*)d_in[3];
  float* out = (float*)d_out;

  unsigned short* qf = (unsigned short*)d_ws;          // frag-major Q [BT/16][4][64][8]
  unsigned short* kf = qf + (size_t)BT * DD;            // frag-major K [BT/32][2][4][64][8]
  unsigned short* vt = kf + (size_t)BT * DD;            // vt2 V^T frag layout
  unsigned short* fq = vt + (size_t)BT * DD;            // frag-major W (16384 each)
  unsigned short* fk = fq + DD * DD;
  unsigned short* fv = fk + DD * DD;

  dim3 wt_grid(64, 3);
  wt_kernel<<<wt_grid, 256, 0, stream>>>(Wq, Wk, Wv, fq, fk, fv);
  proj_kernel<<<BT / 32, 256, 0, stream>>>(X, fq, fk, fv, qf, kf, vt);
  attn_kernel<<<256, 256, 0, stream>>>(qf, kf, vt, out);
}